// Round 1
// baseline (2097.961 us; speedup 1.0000x reference)
//
#include <hip/hip_runtime.h>

namespace {

constexpr int B_  = 16;
constexpr int L_  = 4096;   // 64*64
constexpr int DI_ = 128;
constexpr int KG_ = 4;

// workspace offsets (in floats)
constexpr size_t OFF_PROJ   = 0;                                  // (B,L,128)
constexpr size_t OFF_ZS     = OFF_PROJ + (size_t)B_*L_*DI_;       // (B,L,128)
constexpr size_t OFF_BC     = OFF_ZS   + (size_t)B_*L_*DI_;       // (B,K,L,32)
constexpr size_t OFF_Y      = OFF_BC   + (size_t)B_*KG_*L_*32;    // (B,K,L,128)
constexpr size_t OFF_DELTA  = OFF_Y    + (size_t)B_*KG_*L_*DI_;   // (B,K,L,128)
constexpr size_t OFF_FUSION = OFF_DELTA;                          // alias (B,L,64) after k3
constexpr size_t OFF_H1     = OFF_FUSION + (size_t)B_*L_*64;      // alias (B,L,256)
constexpr size_t WS_FLOATS  = OFF_DELTA + (size_t)B_*KG_*L_*DI_;  // ~369 MB

__device__ __forceinline__ int perm_k(int k, int l) {
  int s = (k & 2) ? (L_ - 1 - l) : l;
  if (k & 1) s = ((s & 63) << 6) | (s >> 6);
  return s;
}
__device__ __forceinline__ float sp_f(float x) {       // softplus
  return (x > 20.f) ? x : log1pf(__expf(x));
}
__device__ __forceinline__ float silu_f(float x) {
  return x / (1.f + __expf(-x));
}

// ---------------- K1: input LN + projection (both modalities) ----------------
__global__ __launch_bounds__(256) void k1_stage1(
    const float* __restrict__ x0, const float* __restrict__ x1,
    const float* __restrict__ ing, const float* __restrict__ inb,
    const float* __restrict__ projw,   // (2,256,64)
    float* __restrict__ proj, float* __restrict__ zs)
{
  __shared__ __align__(16) float s0[64*68];
  __shared__ __align__(16) float s1[64*68];
  __shared__ float gg[64], bb[64];
  const int t = threadIdx.x;
  const int b = blockIdx.x >> 6, h = blockIdx.x & 63;
  if (t < 64) { gg[t] = ing[t]; bb[t] = inb[t]; }
  const size_t ibase = ((size_t)b*64)*4096 + (size_t)h*64;  // + c*4096 + w
  for (int rep = 0; rep < 16; ++rep) {
    int idx = rep*256 + t;
    int c = idx >> 6, w = idx & 63;
    s0[c*68+w] = x0[ibase + (size_t)c*4096 + w];
    s1[c*68+w] = x1[ibase + (size_t)c*4096 + w];
  }
  __syncthreads();
  const int w = t >> 2, j = t & 3;
  float sm0=0.f, sq0=0.f, sm1=0.f, sq1=0.f;
  #pragma unroll
  for (int cc = 0; cc < 16; ++cc) {
    float v0 = s0[(j*16+cc)*68 + w]; sm0 += v0; sq0 += v0*v0;
    float v1 = s1[(j*16+cc)*68 + w]; sm1 += v1; sq1 += v1*v1;
  }
  sm0 += __shfl_xor(sm0,1); sq0 += __shfl_xor(sq0,1);
  sm1 += __shfl_xor(sm1,1); sq1 += __shfl_xor(sq1,1);
  sm0 += __shfl_xor(sm0,2); sq0 += __shfl_xor(sq0,2);
  sm1 += __shfl_xor(sm1,2); sq1 += __shfl_xor(sq1,2);
  const float mu0 = sm0*(1.f/64.f), mu1 = sm1*(1.f/64.f);
  const float rs0 = rsqrtf(sq0*(1.f/64.f) - mu0*mu0 + 1e-5f);
  const float rs1 = rsqrtf(sq1*(1.f/64.f) - mu1*mu1 + 1e-5f);
  float v0r[16], v1r[16];
  #pragma unroll
  for (int cc = 0; cc < 16; ++cc) {
    int c = j*16+cc;
    v0r[cc] = (s0[c*68+w]-mu0)*rs0*gg[c] + bb[c];
    v1r[cc] = (s1[c*68+w]-mu1)*rs1*gg[c] + bb[c];
  }
  __syncthreads();
  #pragma unroll
  for (int cc = 0; cc < 16; ++cc) {          // transpose to [w][c]
    int c = j*16+cc;
    s0[w*68+c] = v0r[cc];
    s1[w*68+c] = v1r[cc];
  }
  __syncthreads();
  // matmul: thread -> weight row ro; ro<128 is p-part (summed), ro>=128 is z-part
  const int ro = t;
  const float* W0 = projw + ro*64;
  const float* W1 = projw + 256*64 + ro*64;
  const size_t obase = ((size_t)b*4096 + (size_t)h*64)*128;
  for (int wh = 0; wh < 2; ++wh) {
    float a0[32], a1[32];
    #pragma unroll
    for (int i = 0; i < 32; ++i) { a0[i]=0.f; a1[i]=0.f; }
    for (int ch = 0; ch < 4; ++ch) {
      float4 w0v[4], w1v[4];
      #pragma unroll
      for (int q = 0; q < 4; ++q) {
        w0v[q] = *reinterpret_cast<const float4*>(W0 + ch*16 + q*4);
        w1v[q] = *reinterpret_cast<const float4*>(W1 + ch*16 + q*4);
      }
      #pragma unroll
      for (int ww = 0; ww < 32; ++ww) {
        const float* r0 = &s0[(wh*32+ww)*68 + ch*16];
        const float* r1 = &s1[(wh*32+ww)*68 + ch*16];
        float acc0 = 0.f, acc1 = 0.f;
        #pragma unroll
        for (int q = 0; q < 4; ++q) {
          float4 xa = *reinterpret_cast<const float4*>(r0 + q*4);
          float4 xb = *reinterpret_cast<const float4*>(r1 + q*4);
          acc0 += xa.x*w0v[q].x + xa.y*w0v[q].y + xa.z*w0v[q].z + xa.w*w0v[q].w;
          acc1 += xb.x*w1v[q].x + xb.y*w1v[q].y + xb.z*w1v[q].z + xb.w*w1v[q].w;
        }
        a0[ww] += acc0; a1[ww] += acc1;
      }
    }
    if (ro < 128) {
      #pragma unroll
      for (int ww = 0; ww < 32; ++ww) {
        int wloc = wh*32+ww;
        proj[obase + (size_t)wloc*128 + ro] = a0[ww] + a1[ww];
      }
    } else {
      #pragma unroll
      for (int ww = 0; ww < 32; ++ww) {
        int wloc = wh*32+ww;
        zs[obase + (size_t)wloc*128 + (ro-128)] = silu_f(a0[ww]) + silu_f(a1[ww]);
      }
    }
  }
}

// ---------------- K2: x_dbl + dt-proj + softplus ----------------
__global__ __launch_bounds__(256) void k2_xproj(
    const float* __restrict__ proj,
    const float* __restrict__ xpw,   // (4,36,128)
    const float* __restrict__ dtw,   // (4,128,4)
    const float* __restrict__ dtb,   // (4,128)
    float* __restrict__ bc,          // (B,K,L,32)
    float* __restrict__ delta)       // (B,K,L,128)
{
  __shared__ __align__(16) float X[64*132];
  __shared__ __align__(16) float Wp[36*128];
  __shared__ float xdb[64*37];
  __shared__ float dtwT[4*128];
  __shared__ float biasS[128];
  const int t = threadIdx.x;
  const int lt = blockIdx.x & 63;
  const int k  = (blockIdx.x >> 6) & 3;
  const int b  = blockIdx.x >> 8;
  const int l0 = lt*64;
  const size_t pb = (size_t)b*4096;
  for (int rep = 0; rep < 32; ++rep) {
    int idx = rep*256 + t;
    int i = idx >> 7, d = idx & 127;
    X[i*132+d] = proj[(pb + perm_k(k, l0+i))*128 + d];
  }
  for (int idx = t; idx < 36*128; idx += 256) Wp[idx] = xpw[k*36*128 + idx];
  if (t < 128) {
    #pragma unroll
    for (int r = 0; r < 4; ++r) dtwT[r*128+t] = dtw[(k*128 + t)*4 + r];
    biasS[t] = dtb[k*128+t];
  }
  __syncthreads();
  {
    const int l = t & 63, cg = t >> 6;
    float acc[9];
    #pragma unroll
    for (int cj = 0; cj < 9; ++cj) acc[cj]=0.f;
    for (int dc = 0; dc < 32; ++dc) {
      float4 xv = *reinterpret_cast<const float4*>(&X[l*132 + dc*4]);
      #pragma unroll
      for (int cj = 0; cj < 9; ++cj) {
        float4 wv = *reinterpret_cast<const float4*>(&Wp[(cg*9+cj)*128 + dc*4]);
        acc[cj] += xv.x*wv.x + xv.y*wv.y + xv.z*wv.z + xv.w*wv.w;
      }
    }
    #pragma unroll
    for (int cj = 0; cj < 9; ++cj) xdb[l*37 + cg*9+cj] = acc[cj];
  }
  __syncthreads();
  const size_t sb = ((size_t)(b*4+k))*4096;
  for (int rep = 0; rep < 8; ++rep) {
    int idx = rep*256 + t;
    int i = idx >> 5, jj = idx & 31;
    bc[(sb + l0+i)*32 + jj] = xdb[i*37 + 4 + jj];
  }
  {
    const int d = t & 127, lp = t >> 7;
    const float w0 = dtwT[0*128+d], w1 = dtwT[1*128+d];
    const float w2 = dtwT[2*128+d], w3 = dtwT[3*128+d];
    const float bi = biasS[d];
    for (int ii = 0; ii < 32; ++ii) {
      int i = ii*2 + lp;
      float dt = xdb[i*37+0]*w0 + xdb[i*37+1]*w1 + xdb[i*37+2]*w2 + xdb[i*37+3]*w3 + bi;
      delta[(sb + l0+i)*128 + d] = sp_f(dt);
    }
  }
}

// ---------------- K3: selective scan ----------------
__global__ __launch_bounds__(256) void k3_scan(
    const float* __restrict__ proj,
    const float* __restrict__ delta,
    const float* __restrict__ bc,
    const float* __restrict__ alog,  // (512,16)
    const float* __restrict__ Dsv,   // (512)
    float* __restrict__ y)           // (B,K,L,128)
{
  __shared__ float ldl[32*16], lx[32*16], lbc[32*32], ly[32*16];
  const int t = threadIdx.x;
  const int n = t & 15, dq = t >> 4;
  const int dg = blockIdx.x & 7;
  const int k  = (blockIdx.x >> 3) & 3;
  const int b  = blockIdx.x >> 5;
  const int d  = dg*16 + dq;
  const float A  = -expf(alog[(k*128+d)*16 + n]);
  const float Dd = Dsv[k*128+d];
  const size_t sb = ((size_t)(b*4+k))*4096;
  const size_t pb = (size_t)b*4096;
  float h = 0.f;
  for (int wnd = 0; wnd < 128; ++wnd) {
    const int lw0 = wnd*32;
    #pragma unroll
    for (int rep = 0; rep < 2; ++rep) {
      int idx = rep*256 + t;
      int i = idx >> 4, dd = idx & 15;
      ldl[idx] = delta[(sb + lw0+i)*128 + dg*16+dd];
      lx[idx]  = proj[(pb + perm_k(k, lw0+i))*128 + dg*16+dd];
    }
    #pragma unroll
    for (int rep = 0; rep < 4; ++rep) {
      int idx = rep*256 + t;
      lbc[idx] = bc[(sb + lw0 + (idx>>5))*32 + (idx&31)];
    }
    __syncthreads();
    #pragma unroll 8
    for (int i = 0; i < 32; ++i) {
      float dl = ldl[i*16+dq];
      float xv = lx[i*16+dq];
      float dA = __expf(dl*A);
      h = dA*h + dl*xv*lbc[i*32+n];
      float r = h*lbc[i*32+16+n];
      r += __shfl_xor(r,1); r += __shfl_xor(r,2);
      r += __shfl_xor(r,4); r += __shfl_xor(r,8);
      if (n == 0) ly[i*16+dq] = r + Dd*xv;
    }
    __syncthreads();
    {
      int idx = t;
      y[(sb + lw0 + (idx>>4))*128 + dg*16 + (idx&15)] = ly[idx];
      idx = 256 + t;
      y[(sb + lw0 + (idx>>4))*128 + dg*16 + (idx&15)] = ly[idx];
    }
    __syncthreads();
  }
}

// ---------------- K4: merge + out-LN + z-gate + out_proj + skip ----------------
__global__ __launch_bounds__(256) void k4_merge(
    const float* __restrict__ y,
    const float* __restrict__ zs,
    const float* __restrict__ ong, const float* __restrict__ onb,
    const float* __restrict__ opw,  // (64,128)
    const float* __restrict__ x0, const float* __restrict__ x1,
    float* __restrict__ fusion)     // (B,L,64)
{
  __shared__ __align__(16) float ym[64*132];
  __shared__ float xs2[64*68];
  __shared__ float g2[128], b2[128];
  const int t = threadIdx.x;
  const int b = blockIdx.x >> 6, h = blockIdx.x & 63;
  if (t < 128) { g2[t] = ong[t]; b2[t] = onb[t]; }
  const size_t yb = ((size_t)b*4)*4096*128;
  for (int rep = 0; rep < 32; ++rep) {
    int idx = rep*256 + t;
    int w = idx >> 7, dd = idx & 127;
    int l = h*64 + w;
    int p1l = ((l & 63) << 6) | (l >> 6);
    float v = y[yb + ((size_t)0*4096 + l)*128 + dd]
            + y[yb + ((size_t)1*4096 + p1l)*128 + dd]
            + y[yb + ((size_t)2*4096 + (4095-l))*128 + dd]
            + y[yb + ((size_t)3*4096 + (4095-p1l))*128 + dd];
    ym[w*132+dd] = v;
  }
  const size_t ibase = ((size_t)b*64)*4096 + (size_t)h*64;
  for (int rep = 0; rep < 16; ++rep) {
    int idx = rep*256 + t;
    int c = idx >> 6, w = idx & 63;
    xs2[c*68+w] = x0[ibase + (size_t)c*4096 + w] + x1[ibase + (size_t)c*4096 + w];
  }
  __syncthreads();
  {
    const int w = t >> 2, j = t & 3;
    float sm=0.f, sq=0.f;
    #pragma unroll
    for (int cc = 0; cc < 32; ++cc) {
      float v = ym[w*132 + j*32+cc];
      sm += v; sq += v*v;
    }
    sm += __shfl_xor(sm,1); sq += __shfl_xor(sq,1);
    sm += __shfl_xor(sm,2); sq += __shfl_xor(sq,2);
    float mu = sm*(1.f/128.f);
    float rs = rsqrtf(sq*(1.f/128.f) - mu*mu + 1e-5f);
    const size_t zb = ((size_t)b*4096 + h*64 + w)*128;
    #pragma unroll
    for (int cc = 0; cc < 32; ++cc) {
      int dd = j*32+cc;
      float v = ym[w*132+dd];
      ym[w*132+dd] = ((v-mu)*rs*g2[dd] + b2[dd]) * zs[zb + dd];
    }
  }
  __syncthreads();
  {
    const int c = t & 63, wg = t >> 6;
    float acc[16];
    #pragma unroll
    for (int i = 0; i < 16; ++i) acc[i]=0.f;
    const float* OW = opw + c*128;
    for (int ch = 0; ch < 8; ++ch) {
      float4 w4[4];
      #pragma unroll
      for (int q = 0; q < 4; ++q) w4[q] = *reinterpret_cast<const float4*>(OW + ch*16 + q*4);
      #pragma unroll
      for (int wi = 0; wi < 16; ++wi) {
        const float* r = &ym[(wg*16+wi)*132 + ch*16];
        float a = 0.f;
        #pragma unroll
        for (int q = 0; q < 4; ++q) {
          float4 yv = *reinterpret_cast<const float4*>(r + q*4);
          a += yv.x*w4[q].x + yv.y*w4[q].y + yv.z*w4[q].z + yv.w*w4[q].w;
        }
        acc[wi] += a;
      }
    }
    const size_t fb = ((size_t)b*4096 + h*64)*64;
    #pragma unroll
    for (int wi = 0; wi < 16; ++wi) {
      int w = wg*16+wi;
      fusion[fb + (size_t)w*64 + c] = acc[wi] + xs2[c*68+w];
    }
  }
}

// ---------------- K5a: fc1 + exact GELU ----------------
__global__ __launch_bounds__(256) void k5a_fc1(
    const float* __restrict__ fusion,
    const float* __restrict__ w1, const float* __restrict__ b1,
    float* __restrict__ h1)
{
  __shared__ __align__(16) float f[64*68];
  const int t = threadIdx.x;
  const size_t pos0 = (size_t)blockIdx.x * 64;
  for (int rep = 0; rep < 16; ++rep) {
    int idx = rep*256 + t;
    int i = idx >> 6, c = idx & 63;
    f[i*68+c] = fusion[(pos0+i)*64 + c];
  }
  __syncthreads();
  const int o = t;
  float acc[64];
  #pragma unroll
  for (int i = 0; i < 64; ++i) acc[i]=0.f;
  const float* W = w1 + o*64;
  for (int ch = 0; ch < 4; ++ch) {
    float4 wv[4];
    #pragma unroll
    for (int q = 0; q < 4; ++q) wv[q] = *reinterpret_cast<const float4*>(W + ch*16 + q*4);
    #pragma unroll
    for (int i = 0; i < 64; ++i) {
      const float* r = &f[i*68 + ch*16];
      float a = 0.f;
      #pragma unroll
      for (int q = 0; q < 4; ++q) {
        float4 xv = *reinterpret_cast<const float4*>(r + q*4);
        a += xv.x*wv[q].x + xv.y*wv[q].y + xv.z*wv[q].z + xv.w*wv[q].w;
      }
      acc[i] += a;
    }
  }
  const float bias = b1[o];
  #pragma unroll
  for (int i = 0; i < 64; ++i) {
    float x = acc[i] + bias;
    h1[(pos0+i)*256 + o] = 0.5f*x*(1.f + erff(x*0.70710678f));
  }
}

// ---------------- K5b: fc2 + final LN ----------------
__global__ __launch_bounds__(256) void k5b_fc2ln(
    const float* __restrict__ h1,
    const float* __restrict__ w2, const float* __restrict__ b2,
    const float* __restrict__ lg, const float* __restrict__ lb,
    float* __restrict__ out)
{
  __shared__ __align__(16) float hh[8*256];
  __shared__ float h2[8*768];
  __shared__ float lmu[8], lrs[8];
  const int t = threadIdx.x;
  const size_t pos0 = (size_t)blockIdx.x * 8;
  for (int rep = 0; rep < 8; ++rep) {
    int idx = rep*256 + t;
    hh[idx] = h1[(pos0 + (idx >> 8))*256 + (idx & 255)];
  }
  __syncthreads();
  {
    const int p = t;
    float acc[3][8];
    #pragma unroll
    for (int e = 0; e < 3; ++e)
      #pragma unroll
      for (int i = 0; i < 8; ++i) acc[e][i]=0.f;
    for (int ch = 0; ch < 16; ++ch) {
      float4 wv[3][4];
      #pragma unroll
      for (int e = 0; e < 3; ++e)
        #pragma unroll
        for (int q = 0; q < 4; ++q)
          wv[e][q] = *reinterpret_cast<const float4*>(w2 + (size_t)(p+e*256)*256 + ch*16 + q*4);
      #pragma unroll
      for (int i = 0; i < 8; ++i) {
        float4 hv[4];
        #pragma unroll
        for (int q = 0; q < 4; ++q) hv[q] = *reinterpret_cast<const float4*>(&hh[i*256 + ch*16 + q*4]);
        #pragma unroll
        for (int e = 0; e < 3; ++e) {
          float a=0.f;
          #pragma unroll
          for (int q = 0; q < 4; ++q)
            a += hv[q].x*wv[e][q].x + hv[q].y*wv[e][q].y + hv[q].z*wv[e][q].z + hv[q].w*wv[e][q].w;
          acc[e][i] += a;
        }
      }
    }
    #pragma unroll
    for (int e = 0; e < 3; ++e) {
      float bias = b2[p + e*256];
      #pragma unroll
      for (int i = 0; i < 8; ++i) h2[i*768 + p + e*256] = acc[e][i] + bias;
    }
  }
  __syncthreads();
  {
    const int i = t >> 5, j = t & 31;
    float sm=0.f, sq=0.f;
    #pragma unroll
    for (int cc = 0; cc < 24; ++cc) {
      float v = h2[i*768 + j*24 + cc];
      sm += v; sq += v*v;
    }
    sm += __shfl_xor(sm,1);  sq += __shfl_xor(sq,1);
    sm += __shfl_xor(sm,2);  sq += __shfl_xor(sq,2);
    sm += __shfl_xor(sm,4);  sq += __shfl_xor(sq,4);
    sm += __shfl_xor(sm,8);  sq += __shfl_xor(sq,8);
    sm += __shfl_xor(sm,16); sq += __shfl_xor(sq,16);
    if (j == 0) {
      float mu = sm*(1.f/768.f);
      lmu[i] = mu;
      lrs[i] = rsqrtf(sq*(1.f/768.f) - mu*mu + 1e-5f);
    }
  }
  __syncthreads();
  for (int rep = 0; rep < 24; ++rep) {
    int idx = rep*256 + t;       // < 6144
    int i = idx / 768, c = idx % 768;
    out[(pos0+i)*768 + c] = (h2[i*768+c]-lmu[i])*lrs[i]*lg[c] + lb[c];
  }
}

} // namespace

extern "C" void kernel_launch(void* const* d_in, const int* in_sizes, int n_in,
                              void* d_out, int out_size, void* d_ws, size_t ws_size,
                              hipStream_t stream) {
  const float* x0   = (const float*)d_in[0];
  const float* x1   = (const float*)d_in[1];
  const float* ing  = (const float*)d_in[2];
  const float* inb  = (const float*)d_in[3];
  const float* projw= (const float*)d_in[4];
  const float* xpw  = (const float*)d_in[5];
  const float* dtw  = (const float*)d_in[6];
  const float* alog = (const float*)d_in[7];
  const float* Dsv  = (const float*)d_in[8];
  const float* ong  = (const float*)d_in[9];
  const float* onb  = (const float*)d_in[10];
  const float* opw  = (const float*)d_in[11];
  const float* w1   = (const float*)d_in[12];
  const float* b1   = (const float*)d_in[13];
  const float* w2   = (const float*)d_in[14];
  const float* b2   = (const float*)d_in[15];
  const float* lg   = (const float*)d_in[16];
  const float* lb   = (const float*)d_in[17];
  const float* dtb  = (const float*)d_in[18];  // dt_projs_bias added last in dict

  if (ws_size < WS_FLOATS*sizeof(float)) return;  // ws too small -> visible clean fail

  float* ws     = (float*)d_ws;
  float* proj   = ws + OFF_PROJ;
  float* zsb    = ws + OFF_ZS;
  float* bcb    = ws + OFF_BC;
  float* yb     = ws + OFF_Y;
  float* delta  = ws + OFF_DELTA;
  float* fusion = ws + OFF_FUSION;
  float* h1b    = ws + OFF_H1;
  float* out    = (float*)d_out;

  k1_stage1<<<1024, 256, 0, stream>>>(x0, x1, ing, inb, projw, proj, zsb);
  k2_xproj <<<4096, 256, 0, stream>>>(proj, xpw, dtw, dtb, bcb, delta);
  k3_scan  <<<512,  256, 0, stream>>>(proj, delta, bcb, alog, Dsv, yb);
  k4_merge <<<1024, 256, 0, stream>>>(yb, zsb, ong, onb, opw, x0, x1, fusion);
  k5a_fc1  <<<1024, 256, 0, stream>>>(fusion, w1, b1, h1b);
  k5b_fc2ln<<<8192, 256, 0, stream>>>(h1b, w2, b2, lg, lb, out);
}

// Round 2
// 1903.270 us; speedup vs baseline: 1.1023x; 1.1023x over previous
//
#include <hip/hip_runtime.h>

namespace {

constexpr int B_  = 16;
constexpr int L_  = 4096;   // 64*64
constexpr int DI_ = 128;
constexpr int KG_ = 4;
constexpr int NC_ = 4;      // scan chunks
constexpr int CL_ = L_ / NC_;  // 1024 steps per chunk

// workspace offsets (in floats)
constexpr size_t OFF_PROJ   = 0;                                  // (B,L,128)
constexpr size_t OFF_ZS     = OFF_PROJ + (size_t)B_*L_*DI_;       // (B,L,128)
constexpr size_t OFF_BC     = OFF_ZS   + (size_t)B_*L_*DI_;       // (B,K,L,32)
constexpr size_t OFF_Y      = OFF_BC   + (size_t)B_*KG_*L_*32;    // (B,K,L,128)
constexpr size_t OFF_DELTA  = OFF_Y    + (size_t)B_*KG_*L_*DI_;   // (B,K,L,128)
constexpr size_t OFF_FUSION = OFF_DELTA;                          // alias (B,L,64) after k3
constexpr size_t OFF_H1     = OFF_FUSION + (size_t)B_*L_*64;      // alias (B,L,256)
constexpr size_t WS_FLOATS  = OFF_DELTA + (size_t)B_*KG_*L_*DI_;  // ~369 MB

// scratch inside d_out (dead until k5b writes it):
constexpr size_t SC_P    = 0;                 // (2048 blocks)*256
constexpr size_t SC_HEND = 524288;
constexpr size_t SC_HIN  = 1048576;           // total 1.57M floats << out_size

__device__ __forceinline__ int perm_k(int k, int l) {
  int s = (k & 2) ? (L_ - 1 - l) : l;
  if (k & 1) s = ((s & 63) << 6) | (s >> 6);
  return s;
}
__device__ __forceinline__ float sp_f(float x) {       // softplus
  return (x > 20.f) ? x : log1pf(__expf(x));
}
__device__ __forceinline__ float silu_f(float x) {
  return x / (1.f + __expf(-x));
}

// ---------------- K1: input LN + projection (both modalities) ----------------
__global__ __launch_bounds__(256) void k1_stage1(
    const float* __restrict__ x0, const float* __restrict__ x1,
    const float* __restrict__ ing, const float* __restrict__ inb,
    const float* __restrict__ projw,   // (2,256,64)
    float* __restrict__ proj, float* __restrict__ zs)
{
  __shared__ __align__(16) float s0[64*68];
  __shared__ __align__(16) float s1[64*68];
  __shared__ float gg[64], bb[64];
  const int t = threadIdx.x;
  const int b = blockIdx.x >> 6, h = blockIdx.x & 63;
  if (t < 64) { gg[t] = ing[t]; bb[t] = inb[t]; }
  const size_t ibase = ((size_t)b*64)*4096 + (size_t)h*64;  // + c*4096 + w
  for (int rep = 0; rep < 16; ++rep) {
    int idx = rep*256 + t;
    int c = idx >> 6, w = idx & 63;
    s0[c*68+w] = x0[ibase + (size_t)c*4096 + w];
    s1[c*68+w] = x1[ibase + (size_t)c*4096 + w];
  }
  __syncthreads();
  const int w = t >> 2, j = t & 3;
  float sm0=0.f, sq0=0.f, sm1=0.f, sq1=0.f;
  #pragma unroll
  for (int cc = 0; cc < 16; ++cc) {
    float v0 = s0[(j*16+cc)*68 + w]; sm0 += v0; sq0 += v0*v0;
    float v1 = s1[(j*16+cc)*68 + w]; sm1 += v1; sq1 += v1*v1;
  }
  sm0 += __shfl_xor(sm0,1); sq0 += __shfl_xor(sq0,1);
  sm1 += __shfl_xor(sm1,1); sq1 += __shfl_xor(sq1,1);
  sm0 += __shfl_xor(sm0,2); sq0 += __shfl_xor(sq0,2);
  sm1 += __shfl_xor(sm1,2); sq1 += __shfl_xor(sq1,2);
  const float mu0 = sm0*(1.f/64.f), mu1 = sm1*(1.f/64.f);
  const float rs0 = rsqrtf(sq0*(1.f/64.f) - mu0*mu0 + 1e-5f);
  const float rs1 = rsqrtf(sq1*(1.f/64.f) - mu1*mu1 + 1e-5f);
  float v0r[16], v1r[16];
  #pragma unroll
  for (int cc = 0; cc < 16; ++cc) {
    int c = j*16+cc;
    v0r[cc] = (s0[c*68+w]-mu0)*rs0*gg[c] + bb[c];
    v1r[cc] = (s1[c*68+w]-mu1)*rs1*gg[c] + bb[c];
  }
  __syncthreads();
  #pragma unroll
  for (int cc = 0; cc < 16; ++cc) {          // transpose to [w][c]
    int c = j*16+cc;
    s0[w*68+c] = v0r[cc];
    s1[w*68+c] = v1r[cc];
  }
  __syncthreads();
  // matmul: thread -> weight row ro; ro<128 is p-part (summed), ro>=128 is z-part
  const int ro = t;
  const float* W0 = projw + ro*64;
  const float* W1 = projw + 256*64 + ro*64;
  const size_t obase = ((size_t)b*4096 + (size_t)h*64)*128;
  for (int wh = 0; wh < 2; ++wh) {
    float a0[32], a1[32];
    #pragma unroll
    for (int i = 0; i < 32; ++i) { a0[i]=0.f; a1[i]=0.f; }
    for (int ch = 0; ch < 4; ++ch) {
      float4 w0v[4], w1v[4];
      #pragma unroll
      for (int q = 0; q < 4; ++q) {
        w0v[q] = *reinterpret_cast<const float4*>(W0 + ch*16 + q*4);
        w1v[q] = *reinterpret_cast<const float4*>(W1 + ch*16 + q*4);
      }
      #pragma unroll
      for (int ww = 0; ww < 32; ++ww) {
        const float* r0 = &s0[(wh*32+ww)*68 + ch*16];
        const float* r1 = &s1[(wh*32+ww)*68 + ch*16];
        float acc0 = 0.f, acc1 = 0.f;
        #pragma unroll
        for (int q = 0; q < 4; ++q) {
          float4 xa = *reinterpret_cast<const float4*>(r0 + q*4);
          float4 xb = *reinterpret_cast<const float4*>(r1 + q*4);
          acc0 += xa.x*w0v[q].x + xa.y*w0v[q].y + xa.z*w0v[q].z + xa.w*w0v[q].w;
          acc1 += xb.x*w1v[q].x + xb.y*w1v[q].y + xb.z*w1v[q].z + xb.w*w1v[q].w;
        }
        a0[ww] += acc0; a1[ww] += acc1;
      }
    }
    if (ro < 128) {
      #pragma unroll
      for (int ww = 0; ww < 32; ++ww) {
        int wloc = wh*32+ww;
        proj[obase + (size_t)wloc*128 + ro] = a0[ww] + a1[ww];
      }
    } else {
      #pragma unroll
      for (int ww = 0; ww < 32; ++ww) {
        int wloc = wh*32+ww;
        zs[obase + (size_t)wloc*128 + (ro-128)] = silu_f(a0[ww]) + silu_f(a1[ww]);
      }
    }
  }
}

// ---------------- K2: x_dbl + dt-proj + softplus ----------------
__global__ __launch_bounds__(256) void k2_xproj(
    const float* __restrict__ proj,
    const float* __restrict__ xpw,   // (4,36,128)
    const float* __restrict__ dtw,   // (4,128,4)
    const float* __restrict__ dtb,   // (4,128)
    float* __restrict__ bc,          // (B,K,L,32)
    float* __restrict__ delta)       // (B,K,L,128)
{
  __shared__ __align__(16) float X[64*132];
  __shared__ __align__(16) float Wp[36*128];
  __shared__ float xdb[64*37];
  __shared__ float dtwT[4*128];
  __shared__ float biasS[128];
  const int t = threadIdx.x;
  const int lt = blockIdx.x & 63;
  const int k  = (blockIdx.x >> 6) & 3;
  const int b  = blockIdx.x >> 8;
  const int l0 = lt*64;
  const size_t pb = (size_t)b*4096;
  for (int rep = 0; rep < 32; ++rep) {
    int idx = rep*256 + t;
    int i = idx >> 7, d = idx & 127;
    X[i*132+d] = proj[(pb + perm_k(k, l0+i))*128 + d];
  }
  for (int idx = t; idx < 36*128; idx += 256) Wp[idx] = xpw[k*36*128 + idx];
  if (t < 128) {
    #pragma unroll
    for (int r = 0; r < 4; ++r) dtwT[r*128+t] = dtw[(k*128 + t)*4 + r];
    biasS[t] = dtb[k*128+t];
  }
  __syncthreads();
  {
    const int l = t & 63, cg = t >> 6;
    float acc[9];
    #pragma unroll
    for (int cj = 0; cj < 9; ++cj) acc[cj]=0.f;
    for (int dc = 0; dc < 32; ++dc) {
      float4 xv = *reinterpret_cast<const float4*>(&X[l*132 + dc*4]);
      #pragma unroll
      for (int cj = 0; cj < 9; ++cj) {
        float4 wv = *reinterpret_cast<const float4*>(&Wp[(cg*9+cj)*128 + dc*4]);
        acc[cj] += xv.x*wv.x + xv.y*wv.y + xv.z*wv.z + xv.w*wv.w;
      }
    }
    #pragma unroll
    for (int cj = 0; cj < 9; ++cj) xdb[l*37 + cg*9+cj] = acc[cj];
  }
  __syncthreads();
  const size_t sb = ((size_t)(b*4+k))*4096;
  for (int rep = 0; rep < 8; ++rep) {
    int idx = rep*256 + t;
    int i = idx >> 5, jj = idx & 31;
    bc[(sb + l0+i)*32 + jj] = xdb[i*37 + 4 + jj];
  }
  {
    const int d = t & 127, lp = t >> 7;
    const float w0 = dtwT[0*128+d], w1 = dtwT[1*128+d];
    const float w2 = dtwT[2*128+d], w3 = dtwT[3*128+d];
    const float bi = biasS[d];
    for (int ii = 0; ii < 32; ++ii) {
      int i = ii*2 + lp;
      float dt = xdb[i*37+0]*w0 + xdb[i*37+1]*w1 + xdb[i*37+2]*w2 + xdb[i*37+3]*w3 + bi;
      delta[(sb + l0+i)*128 + d] = sp_f(dt);
    }
  }
}

// ---------------- K3a: chunk propagator pass (h from 0; P = prod dA) ----------
// grid: (((b*4+k)*8+dg)*NC + c), 2048 blocks
__global__ __launch_bounds__(256) void k3a_prop(
    const float* __restrict__ proj,
    const float* __restrict__ delta,
    const float* __restrict__ bc,
    const float* __restrict__ alog,
    float* __restrict__ Pout, float* __restrict__ hendout)
{
  __shared__ float ldl[2][512], lx[2][512], lB[2][512];
  const int t = threadIdx.x;
  const int n = t & 15, dq = t >> 4;
  const int c  = blockIdx.x & 3;
  const int dg = (blockIdx.x >> 2) & 7;
  const int k  = (blockIdx.x >> 5) & 3;
  const int b  = blockIdx.x >> 7;
  const int d  = dg*16 + dq;
  const float A = -expf(alog[(k*128+d)*16 + n]);
  const size_t sb = ((size_t)(b*4+k))*4096;
  const size_t pb = (size_t)b*4096;
  const int l0c = c*CL_;
  float h = 0.f, P = 1.f;
  float p_dl[2], p_x[2], p_B[2];

  auto PRELOAD = [&](int wnd){
    int lw0 = l0c + wnd*32;
    #pragma unroll
    for (int rep = 0; rep < 2; ++rep) {
      int idx = rep*256 + t;
      int i = idx >> 4, dd = idx & 15;
      p_dl[rep] = delta[(sb + lw0+i)*128 + dg*16+dd];
      p_x[rep]  = proj[(pb + perm_k(k, lw0+i))*128 + dg*16+dd];
      p_B[rep]  = bc[(sb + lw0+i)*32 + dd];          // B part: cols 0..15
    }
  };
  auto STORE = [&](int buf){
    #pragma unroll
    for (int rep = 0; rep < 2; ++rep) {
      int idx = rep*256 + t;
      ldl[buf][idx] = p_dl[rep];
      lx[buf][idx]  = p_x[rep];
      lB[buf][idx]  = p_B[rep];
    }
  };

  PRELOAD(0); STORE(0); __syncthreads();
  const int NW = CL_/32;
  for (int wnd = 0; wnd < NW; ++wnd) {
    const int cur = wnd & 1;
    if (wnd+1 < NW) PRELOAD(wnd+1);
    #pragma unroll 8
    for (int i = 0; i < 32; ++i) {
      float dl = ldl[cur][i*16+dq];
      float xv = lx[cur][i*16+dq];
      float dA = __expf(dl*A);
      h = dA*h + dl*xv*lB[cur][i*16+n];
      P *= dA;
    }
    if (wnd+1 < NW) STORE(1-cur);
    __syncthreads();
  }
  Pout[(size_t)blockIdx.x*256 + t]    = P;
  hendout[(size_t)blockIdx.x*256 + t] = h;
}

// ---------------- K3b: cross-chunk combine -> h_in per chunk ------------------
__global__ __launch_bounds__(256) void k3b_combine(
    const float* __restrict__ P, const float* __restrict__ hend,
    float* __restrict__ hin)
{
  const int g = blockIdx.x*256 + threadIdx.x;   // 512 blocks * 256 = 131072
  const int bkdg = g >> 8, t8 = g & 255;
  float h = 0.f;
  #pragma unroll
  for (int c = 0; c < NC_; ++c) {
    size_t off = ((size_t)bkdg*NC_ + c)*256 + t8;
    hin[off] = h;
    h = P[off]*h + hend[off];
  }
}

// ---------------- K3c: scan with h_in, produce y ------------------------------
__global__ __launch_bounds__(256) void k3c_scan(
    const float* __restrict__ proj,
    const float* __restrict__ delta,
    const float* __restrict__ bc,
    const float* __restrict__ alog,
    const float* __restrict__ Dsv,
    const float* __restrict__ hin,
    float* __restrict__ y)
{
  __shared__ float ldl[2][512], lx[2][512], lbc[2][1024], ly[2][512];
  const int t = threadIdx.x;
  const int n = t & 15, dq = t >> 4;
  const int c  = blockIdx.x & 3;
  const int dg = (blockIdx.x >> 2) & 7;
  const int k  = (blockIdx.x >> 5) & 3;
  const int b  = blockIdx.x >> 7;
  const int d  = dg*16 + dq;
  const float A  = -expf(alog[(k*128+d)*16 + n]);
  const float Dd = Dsv[k*128+d];
  const size_t sb = ((size_t)(b*4+k))*4096;
  const size_t pb = (size_t)b*4096;
  const int l0c = c*CL_;
  float h = hin[(size_t)blockIdx.x*256 + t];
  float p_dl[2], p_x[2], p_bc[4];

  auto PRELOAD = [&](int wnd){
    int lw0 = l0c + wnd*32;
    #pragma unroll
    for (int rep = 0; rep < 2; ++rep) {
      int idx = rep*256 + t;
      int i = idx >> 4, dd = idx & 15;
      p_dl[rep] = delta[(sb + lw0+i)*128 + dg*16+dd];
      p_x[rep]  = proj[(pb + perm_k(k, lw0+i))*128 + dg*16+dd];
    }
    #pragma unroll
    for (int rep = 0; rep < 4; ++rep) {
      int idx = rep*256 + t;
      p_bc[rep] = bc[(sb + lw0 + (idx>>5))*32 + (idx&31)];
    }
  };
  auto STORE = [&](int buf){
    #pragma unroll
    for (int rep = 0; rep < 2; ++rep) {
      int idx = rep*256 + t;
      ldl[buf][idx] = p_dl[rep];
      lx[buf][idx]  = p_x[rep];
    }
    #pragma unroll
    for (int rep = 0; rep < 4; ++rep) {
      int idx = rep*256 + t;
      lbc[buf][idx] = p_bc[rep];
    }
  };

  PRELOAD(0); STORE(0); __syncthreads();
  const int NW = CL_/32;
  for (int wnd = 0; wnd < NW; ++wnd) {
    const int cur = wnd & 1;
    if (wnd+1 < NW) PRELOAD(wnd+1);
    #pragma unroll 8
    for (int i = 0; i < 32; ++i) {
      float dl = ldl[cur][i*16+dq];
      float xv = lx[cur][i*16+dq];
      float dA = __expf(dl*A);
      h = dA*h + dl*xv*lbc[cur][i*32+n];
      float r = h*lbc[cur][i*32+16+n];
      r += __shfl_xor(r,1); r += __shfl_xor(r,2);
      r += __shfl_xor(r,4); r += __shfl_xor(r,8);
      if (n == 0) ly[cur][i*16+dq] = r + Dd*xv;
    }
    if (wnd+1 < NW) STORE(1-cur);
    __syncthreads();
    {
      const int lw0 = l0c + wnd*32;
      int idx = t;
      y[(sb + lw0 + (idx>>4))*128 + dg*16 + (idx&15)] = ly[cur][idx];
      idx = 256 + t;
      y[(sb + lw0 + (idx>>4))*128 + dg*16 + (idx&15)] = ly[cur][idx];
    }
  }
}

// ---------------- K4: merge + out-LN + z-gate + out_proj + skip ----------------
__global__ __launch_bounds__(256) void k4_merge(
    const float* __restrict__ y,
    const float* __restrict__ zs,
    const float* __restrict__ ong, const float* __restrict__ onb,
    const float* __restrict__ opw,  // (64,128)
    const float* __restrict__ x0, const float* __restrict__ x1,
    float* __restrict__ fusion)     // (B,L,64)
{
  __shared__ __align__(16) float ym[64*132];
  __shared__ float xs2[64*68];
  __shared__ float g2[128], b2[128];
  const int t = threadIdx.x;
  const int b = blockIdx.x >> 6, h = blockIdx.x & 63;
  if (t < 128) { g2[t] = ong[t]; b2[t] = onb[t]; }
  const size_t yb = ((size_t)b*4)*4096*128;
  for (int rep = 0; rep < 32; ++rep) {
    int idx = rep*256 + t;
    int w = idx >> 7, dd = idx & 127;
    int l = h*64 + w;
    int p1l = ((l & 63) << 6) | (l >> 6);
    float v = y[yb + ((size_t)0*4096 + l)*128 + dd]
            + y[yb + ((size_t)1*4096 + p1l)*128 + dd]
            + y[yb + ((size_t)2*4096 + (4095-l))*128 + dd]
            + y[yb + ((size_t)3*4096 + (4095-p1l))*128 + dd];
    ym[w*132+dd] = v;
  }
  const size_t ibase = ((size_t)b*64)*4096 + (size_t)h*64;
  for (int rep = 0; rep < 16; ++rep) {
    int idx = rep*256 + t;
    int c = idx >> 6, w = idx & 63;
    xs2[c*68+w] = x0[ibase + (size_t)c*4096 + w] + x1[ibase + (size_t)c*4096 + w];
  }
  __syncthreads();
  {
    const int w = t >> 2, j = t & 3;
    float sm=0.f, sq=0.f;
    #pragma unroll
    for (int cc = 0; cc < 32; ++cc) {
      float v = ym[w*132 + j*32+cc];
      sm += v; sq += v*v;
    }
    sm += __shfl_xor(sm,1); sq += __shfl_xor(sq,1);
    sm += __shfl_xor(sm,2); sq += __shfl_xor(sq,2);
    float mu = sm*(1.f/128.f);
    float rs = rsqrtf(sq*(1.f/128.f) - mu*mu + 1e-5f);
    const size_t zb = ((size_t)b*4096 + h*64 + w)*128;
    #pragma unroll
    for (int cc = 0; cc < 32; ++cc) {
      int dd = j*32+cc;
      float v = ym[w*132+dd];
      ym[w*132+dd] = ((v-mu)*rs*g2[dd] + b2[dd]) * zs[zb + dd];
    }
  }
  __syncthreads();
  {
    const int c = t & 63, wg = t >> 6;
    float acc[16];
    #pragma unroll
    for (int i = 0; i < 16; ++i) acc[i]=0.f;
    const float* OW = opw + c*128;
    for (int ch = 0; ch < 8; ++ch) {
      float4 w4[4];
      #pragma unroll
      for (int q = 0; q < 4; ++q) w4[q] = *reinterpret_cast<const float4*>(OW + ch*16 + q*4);
      #pragma unroll
      for (int wi = 0; wi < 16; ++wi) {
        const float* r = &ym[(wg*16+wi)*132 + ch*16];
        float a = 0.f;
        #pragma unroll
        for (int q = 0; q < 4; ++q) {
          float4 yv = *reinterpret_cast<const float4*>(r + q*4);
          a += yv.x*w4[q].x + yv.y*w4[q].y + yv.z*w4[q].z + yv.w*w4[q].w;
        }
        acc[wi] += a;
      }
    }
    const size_t fb = ((size_t)b*4096 + h*64)*64;
    #pragma unroll
    for (int wi = 0; wi < 16; ++wi) {
      int w = wg*16+wi;
      fusion[fb + (size_t)w*64 + c] = acc[wi] + xs2[c*68+w];
    }
  }
}

// ---------------- K5a: fc1 + exact GELU ----------------
__global__ __launch_bounds__(256) void k5a_fc1(
    const float* __restrict__ fusion,
    const float* __restrict__ w1, const float* __restrict__ b1,
    float* __restrict__ h1)
{
  __shared__ __align__(16) float f[64*68];
  const int t = threadIdx.x;
  const size_t pos0 = (size_t)blockIdx.x * 64;
  for (int rep = 0; rep < 16; ++rep) {
    int idx = rep*256 + t;
    int i = idx >> 6, c = idx & 63;
    f[i*68+c] = fusion[(pos0+i)*64 + c];
  }
  __syncthreads();
  const int o = t;
  float acc[64];
  #pragma unroll
  for (int i = 0; i < 64; ++i) acc[i]=0.f;
  const float* W = w1 + o*64;
  for (int ch = 0; ch < 4; ++ch) {
    float4 wv[4];
    #pragma unroll
    for (int q = 0; q < 4; ++q) wv[q] = *reinterpret_cast<const float4*>(W + ch*16 + q*4);
    #pragma unroll
    for (int i = 0; i < 64; ++i) {
      const float* r = &f[i*68 + ch*16];
      float a = 0.f;
      #pragma unroll
      for (int q = 0; q < 4; ++q) {
        float4 xv = *reinterpret_cast<const float4*>(r + q*4);
        a += xv.x*wv[q].x + xv.y*wv[q].y + xv.z*wv[q].z + xv.w*wv[q].w;
      }
      acc[i] += a;
    }
  }
  const float bias = b1[o];
  #pragma unroll
  for (int i = 0; i < 64; ++i) {
    float x = acc[i] + bias;
    h1[(pos0+i)*256 + o] = 0.5f*x*(1.f + erff(x*0.70710678f));
  }
}

// ---------------- K5b: fc2 + final LN ----------------
__global__ __launch_bounds__(256) void k5b_fc2ln(
    const float* __restrict__ h1,
    const float* __restrict__ w2, const float* __restrict__ b2,
    const float* __restrict__ lg, const float* __restrict__ lb,
    float* __restrict__ out)
{
  __shared__ __align__(16) float hh[8*256];
  __shared__ float h2[8*768];
  __shared__ float lmu[8], lrs[8];
  const int t = threadIdx.x;
  const size_t pos0 = (size_t)blockIdx.x * 8;
  for (int rep = 0; rep < 8; ++rep) {
    int idx = rep*256 + t;
    hh[idx] = h1[(pos0 + (idx >> 8))*256 + (idx & 255)];
  }
  __syncthreads();
  {
    const int p = t;
    float acc[3][8];
    #pragma unroll
    for (int e = 0; e < 3; ++e)
      #pragma unroll
      for (int i = 0; i < 8; ++i) acc[e][i]=0.f;
    for (int ch = 0; ch < 16; ++ch) {
      float4 wv[3][4];
      #pragma unroll
      for (int e = 0; e < 3; ++e)
        #pragma unroll
        for (int q = 0; q < 4; ++q)
          wv[e][q] = *reinterpret_cast<const float4*>(w2 + (size_t)(p+e*256)*256 + ch*16 + q*4);
      #pragma unroll
      for (int i = 0; i < 8; ++i) {
        float4 hv[4];
        #pragma unroll
        for (int q = 0; q < 4; ++q) hv[q] = *reinterpret_cast<const float4*>(&hh[i*256 + ch*16 + q*4]);
        #pragma unroll
        for (int e = 0; e < 3; ++e) {
          float a=0.f;
          #pragma unroll
          for (int q = 0; q < 4; ++q)
            a += hv[q].x*wv[e][q].x + hv[q].y*wv[e][q].y + hv[q].z*wv[e][q].z + hv[q].w*wv[e][q].w;
          acc[e][i] += a;
        }
      }
    }
    #pragma unroll
    for (int e = 0; e < 3; ++e) {
      float bias = b2[p + e*256];
      #pragma unroll
      for (int i = 0; i < 8; ++i) h2[i*768 + p + e*256] = acc[e][i] + bias;
    }
  }
  __syncthreads();
  {
    const int i = t >> 5, j = t & 31;
    float sm=0.f, sq=0.f;
    #pragma unroll
    for (int cc = 0; cc < 24; ++cc) {
      float v = h2[i*768 + j*24 + cc];
      sm += v; sq += v*v;
    }
    sm += __shfl_xor(sm,1);  sq += __shfl_xor(sq,1);
    sm += __shfl_xor(sm,2);  sq += __shfl_xor(sq,2);
    sm += __shfl_xor(sm,4);  sq += __shfl_xor(sq,4);
    sm += __shfl_xor(sm,8);  sq += __shfl_xor(sq,8);
    sm += __shfl_xor(sm,16); sq += __shfl_xor(sq,16);
    if (j == 0) {
      float mu = sm*(1.f/768.f);
      lmu[i] = mu;
      lrs[i] = rsqrtf(sq*(1.f/768.f) - mu*mu + 1e-5f);
    }
  }
  __syncthreads();
  for (int rep = 0; rep < 24; ++rep) {
    int idx = rep*256 + t;       // < 6144
    int i = idx / 768, c = idx % 768;
    out[(pos0+i)*768 + c] = (h2[i*768+c]-lmu[i])*lrs[i]*lg[c] + lb[c];
  }
}

} // namespace

extern "C" void kernel_launch(void* const* d_in, const int* in_sizes, int n_in,
                              void* d_out, int out_size, void* d_ws, size_t ws_size,
                              hipStream_t stream) {
  const float* x0   = (const float*)d_in[0];
  const float* x1   = (const float*)d_in[1];
  const float* ing  = (const float*)d_in[2];
  const float* inb  = (const float*)d_in[3];
  const float* projw= (const float*)d_in[4];
  const float* xpw  = (const float*)d_in[5];
  const float* dtw  = (const float*)d_in[6];
  const float* alog = (const float*)d_in[7];
  const float* Dsv  = (const float*)d_in[8];
  const float* ong  = (const float*)d_in[9];
  const float* onb  = (const float*)d_in[10];
  const float* opw  = (const float*)d_in[11];
  const float* w1   = (const float*)d_in[12];
  const float* b1   = (const float*)d_in[13];
  const float* w2   = (const float*)d_in[14];
  const float* b2   = (const float*)d_in[15];
  const float* lg   = (const float*)d_in[16];
  const float* lb   = (const float*)d_in[17];
  const float* dtb  = (const float*)d_in[18];  // dt_projs_bias added last in dict

  if (ws_size < WS_FLOATS*sizeof(float)) return;  // ws too small -> visible clean fail

  float* ws     = (float*)d_ws;
  float* proj   = ws + OFF_PROJ;
  float* zsb    = ws + OFF_ZS;
  float* bcb    = ws + OFF_BC;
  float* yb     = ws + OFF_Y;
  float* delta  = ws + OFF_DELTA;
  float* fusion = ws + OFF_FUSION;
  float* h1b    = ws + OFF_H1;
  float* out    = (float*)d_out;

  // scan scratch lives in d_out (dead until k5b)
  float* Pp    = out + SC_P;
  float* hendp = out + SC_HEND;
  float* hinp  = out + SC_HIN;

  k1_stage1 <<<1024, 256, 0, stream>>>(x0, x1, ing, inb, projw, proj, zsb);
  k2_xproj  <<<4096, 256, 0, stream>>>(proj, xpw, dtw, dtb, bcb, delta);
  k3a_prop  <<<2048, 256, 0, stream>>>(proj, delta, bcb, alog, Pp, hendp);
  k3b_combine<<<512, 256, 0, stream>>>(Pp, hendp, hinp);
  k3c_scan  <<<2048, 256, 0, stream>>>(proj, delta, bcb, alog, Dsv, hinp, yb);
  k4_merge  <<<1024, 256, 0, stream>>>(yb, zsb, ong, onb, opw, x0, x1, fusion);
  k5a_fc1   <<<1024, 256, 0, stream>>>(fusion, w1, b1, h1b);
  k5b_fc2ln <<<8192, 256, 0, stream>>>(h1b, w2, b2, lg, lb, out);
}

// Round 3
// 1280.361 us; speedup vs baseline: 1.6386x; 1.4865x over previous
//
#include <hip/hip_runtime.h>

namespace {

constexpr int B_  = 16;
constexpr int L_  = 4096;   // 64*64
constexpr int DI_ = 128;
constexpr int KG_ = 4;
constexpr int NC_ = 4;      // scan chunks
constexpr int CL_ = L_ / NC_;  // 1024 steps per chunk

// workspace offsets (in floats)
constexpr size_t OFF_PROJ   = 0;                                  // (B,L,128)
constexpr size_t OFF_ZS     = OFF_PROJ + (size_t)B_*L_*DI_;       // (B,L,128)
constexpr size_t OFF_BC     = OFF_ZS   + (size_t)B_*L_*DI_;       // (B,K,L,32)
constexpr size_t OFF_Y      = OFF_BC   + (size_t)B_*KG_*L_*32;    // (B,K,L,128)
constexpr size_t OFF_DELTA  = OFF_Y    + (size_t)B_*KG_*L_*DI_;   // (B,K,L,128)
constexpr size_t OFF_FUSION = OFF_DELTA;                          // alias (B,L,64) after k3
constexpr size_t WS_FLOATS  = OFF_DELTA + (size_t)B_*KG_*L_*DI_;  // ~369 MB

// after k4, the Y region is dead -> reuse for bf16 fc2 operands
constexpr size_t OFF_W2BF   = OFF_Y;                  // 768*256 bf16 = 98304 floats
constexpr size_t OFF_H1BF   = OFF_Y + 131072;         // (B*L,256) bf16 = 8.39M floats

// scratch inside d_out (dead until k5b writes it):
constexpr size_t SC_P    = 0;                 // (2048 blocks)*256
constexpr size_t SC_HEND = 524288;
constexpr size_t SC_HIN  = 1048576;           // total 1.57M floats << out_size

typedef __attribute__((ext_vector_type(8))) short short8_t;
typedef __attribute__((ext_vector_type(4))) float f32x4_t;

__device__ __forceinline__ int perm_k(int k, int l) {
  int s = (k & 2) ? (L_ - 1 - l) : l;
  if (k & 1) s = ((s & 63) << 6) | (s >> 6);
  return s;
}
__device__ __forceinline__ float sp_f(float x) {       // softplus
  return (x > 20.f) ? x : log1pf(__expf(x));
}
__device__ __forceinline__ float silu_f(float x) {
  return x / (1.f + __expf(-x));
}
__device__ __forceinline__ unsigned short f2bf(float f) {  // RNE f32->bf16
  unsigned u = __float_as_uint(f);
  u += 0x7FFFu + ((u >> 16) & 1u);
  return (unsigned short)(u >> 16);
}

// ---------------- K1: input LN + projection (both modalities) ----------------
__global__ __launch_bounds__(256) void k1_stage1(
    const float* __restrict__ x0, const float* __restrict__ x1,
    const float* __restrict__ ing, const float* __restrict__ inb,
    const float* __restrict__ projw,   // (2,256,64)
    float* __restrict__ proj, float* __restrict__ zs)
{
  __shared__ __align__(16) float s0[64*68];
  __shared__ __align__(16) float s1[64*68];
  __shared__ float gg[64], bb[64];
  const int t = threadIdx.x;
  const int b = blockIdx.x >> 6, h = blockIdx.x & 63;
  if (t < 64) { gg[t] = ing[t]; bb[t] = inb[t]; }
  const size_t ibase = ((size_t)b*64)*4096 + (size_t)h*64;  // + c*4096 + w
  for (int rep = 0; rep < 16; ++rep) {
    int idx = rep*256 + t;
    int c = idx >> 6, w = idx & 63;
    s0[c*68+w] = x0[ibase + (size_t)c*4096 + w];
    s1[c*68+w] = x1[ibase + (size_t)c*4096 + w];
  }
  __syncthreads();
  const int w = t >> 2, j = t & 3;
  float sm0=0.f, sq0=0.f, sm1=0.f, sq1=0.f;
  #pragma unroll
  for (int cc = 0; cc < 16; ++cc) {
    float v0 = s0[(j*16+cc)*68 + w]; sm0 += v0; sq0 += v0*v0;
    float v1 = s1[(j*16+cc)*68 + w]; sm1 += v1; sq1 += v1*v1;
  }
  sm0 += __shfl_xor(sm0,1); sq0 += __shfl_xor(sq0,1);
  sm1 += __shfl_xor(sm1,1); sq1 += __shfl_xor(sq1,1);
  sm0 += __shfl_xor(sm0,2); sq0 += __shfl_xor(sq0,2);
  sm1 += __shfl_xor(sm1,2); sq1 += __shfl_xor(sq1,2);
  const float mu0 = sm0*(1.f/64.f), mu1 = sm1*(1.f/64.f);
  const float rs0 = rsqrtf(sq0*(1.f/64.f) - mu0*mu0 + 1e-5f);
  const float rs1 = rsqrtf(sq1*(1.f/64.f) - mu1*mu1 + 1e-5f);
  float v0r[16], v1r[16];
  #pragma unroll
  for (int cc = 0; cc < 16; ++cc) {
    int c = j*16+cc;
    v0r[cc] = (s0[c*68+w]-mu0)*rs0*gg[c] + bb[c];
    v1r[cc] = (s1[c*68+w]-mu1)*rs1*gg[c] + bb[c];
  }
  __syncthreads();
  #pragma unroll
  for (int cc = 0; cc < 16; ++cc) {          // transpose to [w][c]
    int c = j*16+cc;
    s0[w*68+c] = v0r[cc];
    s1[w*68+c] = v1r[cc];
  }
  __syncthreads();
  // matmul: thread -> weight row ro; ro<128 is p-part (summed), ro>=128 is z-part
  const int ro = t;
  const float* W0 = projw + ro*64;
  const float* W1 = projw + 256*64 + ro*64;
  const size_t obase = ((size_t)b*4096 + (size_t)h*64)*128;
  for (int wh = 0; wh < 2; ++wh) {
    float a0[32], a1[32];
    #pragma unroll
    for (int i = 0; i < 32; ++i) { a0[i]=0.f; a1[i]=0.f; }
    for (int ch = 0; ch < 4; ++ch) {
      float4 w0v[4], w1v[4];
      #pragma unroll
      for (int q = 0; q < 4; ++q) {
        w0v[q] = *reinterpret_cast<const float4*>(W0 + ch*16 + q*4);
        w1v[q] = *reinterpret_cast<const float4*>(W1 + ch*16 + q*4);
      }
      #pragma unroll
      for (int ww = 0; ww < 32; ++ww) {
        const float* r0 = &s0[(wh*32+ww)*68 + ch*16];
        const float* r1 = &s1[(wh*32+ww)*68 + ch*16];
        float acc0 = 0.f, acc1 = 0.f;
        #pragma unroll
        for (int q = 0; q < 4; ++q) {
          float4 xa = *reinterpret_cast<const float4*>(r0 + q*4);
          float4 xb = *reinterpret_cast<const float4*>(r1 + q*4);
          acc0 += xa.x*w0v[q].x + xa.y*w0v[q].y + xa.z*w0v[q].z + xa.w*w0v[q].w;
          acc1 += xb.x*w1v[q].x + xb.y*w1v[q].y + xb.z*w1v[q].z + xb.w*w1v[q].w;
        }
        a0[ww] += acc0; a1[ww] += acc1;
      }
    }
    if (ro < 128) {
      #pragma unroll
      for (int ww = 0; ww < 32; ++ww) {
        int wloc = wh*32+ww;
        proj[obase + (size_t)wloc*128 + ro] = a0[ww] + a1[ww];
      }
    } else {
      #pragma unroll
      for (int ww = 0; ww < 32; ++ww) {
        int wloc = wh*32+ww;
        zs[obase + (size_t)wloc*128 + (ro-128)] = silu_f(a0[ww]) + silu_f(a1[ww]);
      }
    }
  }
}

// ---------------- K2: x_dbl + dt-proj + softplus ----------------
__global__ __launch_bounds__(256) void k2_xproj(
    const float* __restrict__ proj,
    const float* __restrict__ xpw,   // (4,36,128)
    const float* __restrict__ dtw,   // (4,128,4)
    const float* __restrict__ dtb,   // (4,128)
    float* __restrict__ bc,          // (B,K,L,32)
    float* __restrict__ delta)       // (B,K,L,128)
{
  __shared__ __align__(16) float X[64*132];
  __shared__ __align__(16) float Wp[36*128];
  __shared__ float xdb[64*37];
  __shared__ float dtwT[4*128];
  __shared__ float biasS[128];
  const int t = threadIdx.x;
  const int lt = blockIdx.x & 63;
  const int k  = (blockIdx.x >> 6) & 3;
  const int b  = blockIdx.x >> 8;
  const int l0 = lt*64;
  const size_t pb = (size_t)b*4096;
  for (int rep = 0; rep < 32; ++rep) {
    int idx = rep*256 + t;
    int i = idx >> 7, d = idx & 127;
    X[i*132+d] = proj[(pb + perm_k(k, l0+i))*128 + d];
  }
  for (int idx = t; idx < 36*128; idx += 256) Wp[idx] = xpw[k*36*128 + idx];
  if (t < 128) {
    #pragma unroll
    for (int r = 0; r < 4; ++r) dtwT[r*128+t] = dtw[(k*128 + t)*4 + r];
    biasS[t] = dtb[k*128+t];
  }
  __syncthreads();
  {
    const int l = t & 63, cg = t >> 6;
    float acc[9];
    #pragma unroll
    for (int cj = 0; cj < 9; ++cj) acc[cj]=0.f;
    for (int dc = 0; dc < 32; ++dc) {
      float4 xv = *reinterpret_cast<const float4*>(&X[l*132 + dc*4]);
      #pragma unroll
      for (int cj = 0; cj < 9; ++cj) {
        float4 wv = *reinterpret_cast<const float4*>(&Wp[(cg*9+cj)*128 + dc*4]);
        acc[cj] += xv.x*wv.x + xv.y*wv.y + xv.z*wv.z + xv.w*wv.w;
      }
    }
    #pragma unroll
    for (int cj = 0; cj < 9; ++cj) xdb[l*37 + cg*9+cj] = acc[cj];
  }
  __syncthreads();
  const size_t sb = ((size_t)(b*4+k))*4096;
  for (int rep = 0; rep < 8; ++rep) {
    int idx = rep*256 + t;
    int i = idx >> 5, jj = idx & 31;
    bc[(sb + l0+i)*32 + jj] = xdb[i*37 + 4 + jj];
  }
  {
    const int d = t & 127, lp = t >> 7;
    const float w0 = dtwT[0*128+d], w1 = dtwT[1*128+d];
    const float w2 = dtwT[2*128+d], w3 = dtwT[3*128+d];
    const float bi = biasS[d];
    for (int ii = 0; ii < 32; ++ii) {
      int i = ii*2 + lp;
      float dt = xdb[i*37+0]*w0 + xdb[i*37+1]*w1 + xdb[i*37+2]*w2 + xdb[i*37+3]*w3 + bi;
      delta[(sb + l0+i)*128 + d] = sp_f(dt);
    }
  }
}

// ---------------- K3a: chunk propagator pass (h from 0; P = prod dA) ----------
__global__ __launch_bounds__(256) void k3a_prop(
    const float* __restrict__ proj,
    const float* __restrict__ delta,
    const float* __restrict__ bc,
    const float* __restrict__ alog,
    float* __restrict__ Pout, float* __restrict__ hendout)
{
  __shared__ float ldl[2][512], lx[2][512], lB[2][512];
  const int t = threadIdx.x;
  const int n = t & 15, dq = t >> 4;
  const int c  = blockIdx.x & 3;
  const int dg = (blockIdx.x >> 2) & 7;
  const int k  = (blockIdx.x >> 5) & 3;
  const int b  = blockIdx.x >> 7;
  const int d  = dg*16 + dq;
  const float A = -expf(alog[(k*128+d)*16 + n]);
  const size_t sb = ((size_t)(b*4+k))*4096;
  const size_t pb = (size_t)b*4096;
  const int l0c = c*CL_;
  float h = 0.f, P = 1.f;
  float p_dl[2], p_x[2], p_B[2];

  auto PRELOAD = [&](int wnd){
    int lw0 = l0c + wnd*32;
    #pragma unroll
    for (int rep = 0; rep < 2; ++rep) {
      int idx = rep*256 + t;
      int i = idx >> 4, dd = idx & 15;
      p_dl[rep] = delta[(sb + lw0+i)*128 + dg*16+dd];
      p_x[rep]  = proj[(pb + perm_k(k, lw0+i))*128 + dg*16+dd];
      p_B[rep]  = bc[(sb + lw0+i)*32 + dd];          // B part: cols 0..15
    }
  };
  auto STORE = [&](int buf){
    #pragma unroll
    for (int rep = 0; rep < 2; ++rep) {
      int idx = rep*256 + t;
      ldl[buf][idx] = p_dl[rep];
      lx[buf][idx]  = p_x[rep];
      lB[buf][idx]  = p_B[rep];
    }
  };

  PRELOAD(0); STORE(0); __syncthreads();
  const int NW = CL_/32;
  for (int wnd = 0; wnd < NW; ++wnd) {
    const int cur = wnd & 1;
    if (wnd+1 < NW) PRELOAD(wnd+1);
    #pragma unroll 8
    for (int i = 0; i < 32; ++i) {
      float dl = ldl[cur][i*16+dq];
      float xv = lx[cur][i*16+dq];
      float dA = __expf(dl*A);
      h = dA*h + dl*xv*lB[cur][i*16+n];
      P *= dA;
    }
    if (wnd+1 < NW) STORE(1-cur);
    __syncthreads();
  }
  Pout[(size_t)blockIdx.x*256 + t]    = P;
  hendout[(size_t)blockIdx.x*256 + t] = h;
}

// ---------------- K3b: cross-chunk combine -> h_in per chunk ------------------
__global__ __launch_bounds__(256) void k3b_combine(
    const float* __restrict__ P, const float* __restrict__ hend,
    float* __restrict__ hin)
{
  const int g = blockIdx.x*256 + threadIdx.x;   // 512 blocks * 256 = 131072
  const int bkdg = g >> 8, t8 = g & 255;
  float h = 0.f;
  #pragma unroll
  for (int c = 0; c < NC_; ++c) {
    size_t off = ((size_t)bkdg*NC_ + c)*256 + t8;
    hin[off] = h;
    h = P[off]*h + hend[off];
  }
}

// ---------------- K3c: scan with h_in, produce y ------------------------------
__global__ __launch_bounds__(256) void k3c_scan(
    const float* __restrict__ proj,
    const float* __restrict__ delta,
    const float* __restrict__ bc,
    const float* __restrict__ alog,
    const float* __restrict__ Dsv,
    const float* __restrict__ hin,
    float* __restrict__ y)
{
  __shared__ float ldl[2][512], lx[2][512], lbc[2][1024], ly[2][512];
  const int t = threadIdx.x;
  const int n = t & 15, dq = t >> 4;
  const int c  = blockIdx.x & 3;
  const int dg = (blockIdx.x >> 2) & 7;
  const int k  = (blockIdx.x >> 5) & 3;
  const int b  = blockIdx.x >> 7;
  const int d  = dg*16 + dq;
  const float A  = -expf(alog[(k*128+d)*16 + n]);
  const float Dd = Dsv[k*128+d];
  const size_t sb = ((size_t)(b*4+k))*4096;
  const size_t pb = (size_t)b*4096;
  const int l0c = c*CL_;
  float h = hin[(size_t)blockIdx.x*256 + t];
  float p_dl[2], p_x[2], p_bc[4];

  auto PRELOAD = [&](int wnd){
    int lw0 = l0c + wnd*32;
    #pragma unroll
    for (int rep = 0; rep < 2; ++rep) {
      int idx = rep*256 + t;
      int i = idx >> 4, dd = idx & 15;
      p_dl[rep] = delta[(sb + lw0+i)*128 + dg*16+dd];
      p_x[rep]  = proj[(pb + perm_k(k, lw0+i))*128 + dg*16+dd];
    }
    #pragma unroll
    for (int rep = 0; rep < 4; ++rep) {
      int idx = rep*256 + t;
      p_bc[rep] = bc[(sb + lw0 + (idx>>5))*32 + (idx&31)];
    }
  };
  auto STORE = [&](int buf){
    #pragma unroll
    for (int rep = 0; rep < 2; ++rep) {
      int idx = rep*256 + t;
      ldl[buf][idx] = p_dl[rep];
      lx[buf][idx]  = p_x[rep];
    }
    #pragma unroll
    for (int rep = 0; rep < 4; ++rep) {
      int idx = rep*256 + t;
      lbc[buf][idx] = p_bc[rep];
    }
  };

  PRELOAD(0); STORE(0); __syncthreads();
  const int NW = CL_/32;
  for (int wnd = 0; wnd < NW; ++wnd) {
    const int cur = wnd & 1;
    if (wnd+1 < NW) PRELOAD(wnd+1);
    #pragma unroll 8
    for (int i = 0; i < 32; ++i) {
      float dl = ldl[cur][i*16+dq];
      float xv = lx[cur][i*16+dq];
      float dA = __expf(dl*A);
      h = dA*h + dl*xv*lbc[cur][i*32+n];
      float r = h*lbc[cur][i*32+16+n];
      r += __shfl_xor(r,1); r += __shfl_xor(r,2);
      r += __shfl_xor(r,4); r += __shfl_xor(r,8);
      if (n == 0) ly[cur][i*16+dq] = r + Dd*xv;
    }
    if (wnd+1 < NW) STORE(1-cur);
    __syncthreads();
    {
      const int lw0 = l0c + wnd*32;
      int idx = t;
      y[(sb + lw0 + (idx>>4))*128 + dg*16 + (idx&15)] = ly[cur][idx];
      idx = 256 + t;
      y[(sb + lw0 + (idx>>4))*128 + dg*16 + (idx&15)] = ly[cur][idx];
    }
  }
}

// ---------------- K4: merge + out-LN + z-gate + out_proj + skip ----------------
__global__ __launch_bounds__(256) void k4_merge(
    const float* __restrict__ y,
    const float* __restrict__ zs,
    const float* __restrict__ ong, const float* __restrict__ onb,
    const float* __restrict__ opw,  // (64,128)
    const float* __restrict__ x0, const float* __restrict__ x1,
    float* __restrict__ fusion)     // (B,L,64)
{
  __shared__ __align__(16) float ym[64*132];
  __shared__ float xs2[64*68];
  __shared__ float g2[128], b2[128];
  const int t = threadIdx.x;
  const int b = blockIdx.x >> 6, h = blockIdx.x & 63;
  if (t < 128) { g2[t] = ong[t]; b2[t] = onb[t]; }
  const size_t yb = ((size_t)b*4)*4096*128;
  for (int rep = 0; rep < 32; ++rep) {
    int idx = rep*256 + t;
    int w = idx >> 7, dd = idx & 127;
    int l = h*64 + w;
    int p1l = ((l & 63) << 6) | (l >> 6);
    float v = y[yb + ((size_t)0*4096 + l)*128 + dd]
            + y[yb + ((size_t)1*4096 + p1l)*128 + dd]
            + y[yb + ((size_t)2*4096 + (4095-l))*128 + dd]
            + y[yb + ((size_t)3*4096 + (4095-p1l))*128 + dd];
    ym[w*132+dd] = v;
  }
  const size_t ibase = ((size_t)b*64)*4096 + (size_t)h*64;
  for (int rep = 0; rep < 16; ++rep) {
    int idx = rep*256 + t;
    int c = idx >> 6, w = idx & 63;
    xs2[c*68+w] = x0[ibase + (size_t)c*4096 + w] + x1[ibase + (size_t)c*4096 + w];
  }
  __syncthreads();
  {
    const int w = t >> 2, j = t & 3;
    float sm=0.f, sq=0.f;
    #pragma unroll
    for (int cc = 0; cc < 32; ++cc) {
      float v = ym[w*132 + j*32+cc];
      sm += v; sq += v*v;
    }
    sm += __shfl_xor(sm,1); sq += __shfl_xor(sq,1);
    sm += __shfl_xor(sm,2); sq += __shfl_xor(sq,2);
    float mu = sm*(1.f/128.f);
    float rs = rsqrtf(sq*(1.f/128.f) - mu*mu + 1e-5f);
    const size_t zb = ((size_t)b*4096 + h*64 + w)*128;
    #pragma unroll
    for (int cc = 0; cc < 32; ++cc) {
      int dd = j*32+cc;
      float v = ym[w*132+dd];
      ym[w*132+dd] = ((v-mu)*rs*g2[dd] + b2[dd]) * zs[zb + dd];
    }
  }
  __syncthreads();
  {
    const int c = t & 63, wg = t >> 6;
    float acc[16];
    #pragma unroll
    for (int i = 0; i < 16; ++i) acc[i]=0.f;
    const float* OW = opw + c*128;
    for (int ch = 0; ch < 8; ++ch) {
      float4 w4[4];
      #pragma unroll
      for (int q = 0; q < 4; ++q) w4[q] = *reinterpret_cast<const float4*>(OW + ch*16 + q*4);
      #pragma unroll
      for (int wi = 0; wi < 16; ++wi) {
        const float* r = &ym[(wg*16+wi)*132 + ch*16];
        float a = 0.f;
        #pragma unroll
        for (int q = 0; q < 4; ++q) {
          float4 yv = *reinterpret_cast<const float4*>(r + q*4);
          a += yv.x*w4[q].x + yv.y*w4[q].y + yv.z*w4[q].z + yv.w*w4[q].w;
        }
        acc[wi] += a;
      }
    }
    const size_t fb = ((size_t)b*4096 + h*64)*64;
    #pragma unroll
    for (int wi = 0; wi < 16; ++wi) {
      int w = wg*16+wi;
      fusion[fb + (size_t)w*64 + c] = acc[wi] + xs2[c*68+w];
    }
  }
}

// ---------------- W2 -> bf16 conversion (into dead Y region) ----------------
__global__ __launch_bounds__(256) void w2cvt(
    const float* __restrict__ w2, unsigned short* __restrict__ w2bf)
{
  int i = (blockIdx.x*256 + threadIdx.x)*8;   // 96*256*8 = 196608 exact
  float4 a = *reinterpret_cast<const float4*>(w2 + i);
  float4 b = *reinterpret_cast<const float4*>(w2 + i + 4);
  union { unsigned short u[8]; uint4 v; } pk;
  pk.u[0]=f2bf(a.x); pk.u[1]=f2bf(a.y); pk.u[2]=f2bf(a.z); pk.u[3]=f2bf(a.w);
  pk.u[4]=f2bf(b.x); pk.u[5]=f2bf(b.y); pk.u[6]=f2bf(b.z); pk.u[7]=f2bf(b.w);
  *reinterpret_cast<uint4*>(w2bf + i) = pk.v;
}

// ---------------- K5a: fc1 + exact GELU -> bf16 h1 ----------------
__global__ __launch_bounds__(256) void k5a_fc1(
    const float* __restrict__ fusion,
    const float* __restrict__ w1, const float* __restrict__ b1,
    unsigned short* __restrict__ h1bf)
{
  __shared__ __align__(16) float f[64*68];
  const int t = threadIdx.x;
  const size_t pos0 = (size_t)blockIdx.x * 64;
  for (int rep = 0; rep < 16; ++rep) {
    int idx = rep*256 + t;
    int i = idx >> 6, c = idx & 63;
    f[i*68+c] = fusion[(pos0+i)*64 + c];
  }
  __syncthreads();
  const int o = t;
  float acc[64];
  #pragma unroll
  for (int i = 0; i < 64; ++i) acc[i]=0.f;
  const float* W = w1 + o*64;
  for (int ch = 0; ch < 4; ++ch) {
    float4 wv[4];
    #pragma unroll
    for (int q = 0; q < 4; ++q) wv[q] = *reinterpret_cast<const float4*>(W + ch*16 + q*4);
    #pragma unroll
    for (int i = 0; i < 64; ++i) {
      const float* r = &f[i*68 + ch*16];
      float a = 0.f;
      #pragma unroll
      for (int q = 0; q < 4; ++q) {
        float4 xv = *reinterpret_cast<const float4*>(r + q*4);
        a += xv.x*wv[q].x + xv.y*wv[q].y + xv.z*wv[q].z + xv.w*wv[q].w;
      }
      acc[i] += a;
    }
  }
  const float bias = b1[o];
  #pragma unroll
  for (int i = 0; i < 64; ++i) {
    float x = acc[i] + bias;
    float g = 0.5f*x*(1.f + erff(x*0.70710678f));
    h1bf[(pos0+i)*256 + o] = f2bf(g);
  }
}

// ---------------- K5b: bf16 MFMA GEMM (M=65536,N=768,K=256) + final LN --------
// block: 512 thr = 8 waves (2 row x 4 col); BM=64, BN=768; wave tile 32x192.
__global__ __launch_bounds__(512) void k5b_gemm(
    const unsigned short* __restrict__ h1bf,  // (65536,256) bf16
    const unsigned short* __restrict__ w2bf,  // (768,256)  bf16
    const float* __restrict__ bias2,          // (768)
    const float* __restrict__ lg, const float* __restrict__ lb,
    float* __restrict__ out)
{
  __shared__ __align__(16) char smem[81920];       // A 32KB | B 48KB
  // epilogue aliases on top of B region:
  float* sred  = (float*)(smem + 32768);           // [64][4]
  float* sqred = (float*)(smem + 32768 + 1024);    // [64][4]
  float* smu   = (float*)(smem + 32768 + 2048);    // [64]
  float* srs   = (float*)(smem + 32768 + 2304);    // [64]
  float* sbias = (float*)(smem + 32768 + 2560);    // [768]
  float* sg    = (float*)(smem + 32768 + 5632);    // [768]
  float* sb    = (float*)(smem + 32768 + 8704);    // [768]

  const int t    = threadIdx.x;
  const int lane = t & 63;
  const int wid  = t >> 6;
  const int wr   = wid >> 2;          // 0..1
  const int wc   = wid & 3;           // 0..3
  const int lr   = lane & 15;
  const int lk   = lane >> 4;         // 0..3
  const size_t m0 = (size_t)blockIdx.x * 64;

  // ---- stage A tile: 64 rows x 256 k (bf16), XOR-swizzled ----
  #pragma unroll
  for (int p = 0; p < 4; ++p) {
    int idx = p*512 + t;              // 2048 chunks of 8 bf16
    int r = idx >> 5, ch = idx & 31;
    uint4 v = *reinterpret_cast<const uint4*>(h1bf + (m0 + r)*256 + ch*8);
    int off = (r*512 + ch*16) ^ ((r & 7) << 4);
    *reinterpret_cast<uint4*>(smem + off) = v;
  }

  f32x4_t acc[2][12];
  #pragma unroll
  for (int rt = 0; rt < 2; ++rt)
    #pragma unroll
    for (int ct = 0; ct < 12; ++ct) acc[rt][ct] = (f32x4_t)(0.f);

  for (int ks = 0; ks < 8; ++ks) {
    __syncthreads();                  // prev compute done (and A visible at ks=0)
    // ---- stage B tile: 768 rows(n) x 32 k (bf16), XOR-swizzled ----
    #pragma unroll
    for (int p = 0; p < 6; ++p) {
      int idx = p*512 + t;            // 3072 chunks
      int nn = idx >> 2, kc = idx & 3;
      uint4 v = *reinterpret_cast<const uint4*>(w2bf + (size_t)nn*256 + ks*32 + kc*8);
      int off = (nn*64 + kc*16) ^ ((nn & 7) << 4);
      *reinterpret_cast<uint4*>(smem + 32768 + off) = v;
    }
    __syncthreads();
    // ---- fragments + MFMA ----
    short8_t afrag[2];
    #pragma unroll
    for (int rt = 0; rt < 2; ++rt) {
      int row = wr*32 + rt*16 + lr;
      int off = (row*512 + ks*64 + lk*16) ^ ((row & 7) << 4);
      afrag[rt] = *reinterpret_cast<const short8_t*>(smem + off);
    }
    #pragma unroll
    for (int ct = 0; ct < 12; ++ct) {
      int nn = wc*192 + ct*16 + lr;
      int off = (nn*64 + lk*16) ^ ((nn & 7) << 4);
      short8_t bfrag = *reinterpret_cast<const short8_t*>(smem + 32768 + off);
      acc[0][ct] = __builtin_amdgcn_mfma_f32_16x16x32_bf16(afrag[0], bfrag, acc[0][ct], 0, 0, 0);
      acc[1][ct] = __builtin_amdgcn_mfma_f32_16x16x32_bf16(afrag[1], bfrag, acc[1][ct], 0, 0, 0);
    }
  }
  __syncthreads();                    // K-loop done; B region reusable

  // ---- epilogue: bias + LN + store ----
  for (int idx = t; idx < 768; idx += 512) {
    sbias[idx] = bias2[idx];
    sg[idx]    = lg[idx];
    sb[idx]    = lb[idx];
  }
  __syncthreads();

  // add bias, per-row partial sums over this wave's 192 cols
  #pragma unroll
  for (int rt = 0; rt < 2; ++rt) {
    float ps[4], pq[4];
    #pragma unroll
    for (int j = 0; j < 4; ++j) { ps[j]=0.f; pq[j]=0.f; }
    #pragma unroll
    for (int ct = 0; ct < 12; ++ct) {
      int col = wc*192 + ct*16 + lr;
      float bv = sbias[col];
      #pragma unroll
      for (int j = 0; j < 4; ++j) {
        float v = acc[rt][ct][j] + bv;
        acc[rt][ct][j] = v;
        ps[j] += v; pq[j] += v*v;
      }
    }
    #pragma unroll
    for (int j = 0; j < 4; ++j) {
      ps[j] += __shfl_xor(ps[j],1); pq[j] += __shfl_xor(pq[j],1);
      ps[j] += __shfl_xor(ps[j],2); pq[j] += __shfl_xor(pq[j],2);
      ps[j] += __shfl_xor(ps[j],4); pq[j] += __shfl_xor(pq[j],4);
      ps[j] += __shfl_xor(ps[j],8); pq[j] += __shfl_xor(pq[j],8);
      if (lr == 0) {
        int row = wr*32 + rt*16 + lk*4 + j;
        sred[row*4 + wc]  = ps[j];
        sqred[row*4 + wc] = pq[j];
      }
    }
  }
  __syncthreads();
  if (t < 64) {
    float s = sred[t*4] + sred[t*4+1] + sred[t*4+2] + sred[t*4+3];
    float q = sqred[t*4] + sqred[t*4+1] + sqred[t*4+2] + sqred[t*4+3];
    float mu = s * (1.f/768.f);
    smu[t] = mu;
    srs[t] = rsqrtf(q*(1.f/768.f) - mu*mu + 1e-5f);
  }
  __syncthreads();
  #pragma unroll
  for (int rt = 0; rt < 2; ++rt) {
    #pragma unroll
    for (int j = 0; j < 4; ++j) {
      int row = wr*32 + rt*16 + lk*4 + j;
      float mu = smu[row], rs = srs[row];
      #pragma unroll
      for (int ct = 0; ct < 12; ++ct) {
        int col = wc*192 + ct*16 + lr;
        float v = (acc[rt][ct][j] - mu)*rs*sg[col] + sb[col];
        out[(m0 + row)*768 + col] = v;
      }
    }
  }
}

} // namespace

extern "C" void kernel_launch(void* const* d_in, const int* in_sizes, int n_in,
                              void* d_out, int out_size, void* d_ws, size_t ws_size,
                              hipStream_t stream) {
  const float* x0   = (const float*)d_in[0];
  const float* x1   = (const float*)d_in[1];
  const float* ing  = (const float*)d_in[2];
  const float* inb  = (const float*)d_in[3];
  const float* projw= (const float*)d_in[4];
  const float* xpw  = (const float*)d_in[5];
  const float* dtw  = (const float*)d_in[6];
  const float* alog = (const float*)d_in[7];
  const float* Dsv  = (const float*)d_in[8];
  const float* ong  = (const float*)d_in[9];
  const float* onb  = (const float*)d_in[10];
  const float* opw  = (const float*)d_in[11];
  const float* w1   = (const float*)d_in[12];
  const float* b1   = (const float*)d_in[13];
  const float* w2   = (const float*)d_in[14];
  const float* b2   = (const float*)d_in[15];
  const float* lg   = (const float*)d_in[16];
  const float* lb   = (const float*)d_in[17];
  const float* dtb  = (const float*)d_in[18];  // dt_projs_bias added last in dict

  if (ws_size < WS_FLOATS*sizeof(float)) return;  // ws too small -> visible clean fail

  float* ws     = (float*)d_ws;
  float* proj   = ws + OFF_PROJ;
  float* zsb    = ws + OFF_ZS;
  float* bcb    = ws + OFF_BC;
  float* yb     = ws + OFF_Y;
  float* delta  = ws + OFF_DELTA;
  float* fusion = ws + OFF_FUSION;
  unsigned short* w2bf = (unsigned short*)(ws + OFF_W2BF);
  unsigned short* h1bf = (unsigned short*)(ws + OFF_H1BF);
  float* out    = (float*)d_out;

  // scan scratch lives in d_out (dead until k5b)
  float* Pp    = out + SC_P;
  float* hendp = out + SC_HEND;
  float* hinp  = out + SC_HIN;

  k1_stage1 <<<1024, 256, 0, stream>>>(x0, x1, ing, inb, projw, proj, zsb);
  k2_xproj  <<<4096, 256, 0, stream>>>(proj, xpw, dtw, dtb, bcb, delta);
  k3a_prop  <<<2048, 256, 0, stream>>>(proj, delta, bcb, alog, Pp, hendp);
  k3b_combine<<<512, 256, 0, stream>>>(Pp, hendp, hinp);
  k3c_scan  <<<2048, 256, 0, stream>>>(proj, delta, bcb, alog, Dsv, hinp, yb);
  k4_merge  <<<1024, 256, 0, stream>>>(yb, zsb, ong, onb, opw, x0, x1, fusion);
  w2cvt     <<<96,   256, 0, stream>>>(w2, w2bf);          // Y region now dead
  k5a_fc1   <<<1024, 256, 0, stream>>>(fusion, w1, b1, h1bf);
  k5b_gemm  <<<1024, 512, 0, stream>>>(h1bf, w2bf, b2, lg, lb, out);
}